// Round 8
// baseline (131.118 us; speedup 1.0000x reference)
//
#include <hip/hip_runtime.h>
#include <hip/hip_fp16.h>
#include <math.h>

// Problem constants
#define H_IN   256
#define W_IN   256
#define CIN    3
#define COUT   128
#define NB     8
#define KS     3
#define H_OUT  254
#define W_OUT  254
#define ROW_F  (W_IN * CIN)          // 768 floats per input row

typedef float f32x4 __attribute__((ext_vector_type(4)));

// v_fma_mix_f32: acc(f32) += f16(half of wpk) * x(f32)
#define FMA_MIX_LO(acc, wp, xv) \
    asm("v_fma_mix_f32 %0, %1, %2, %0 op_sel:[0,0,0] op_sel_hi:[1,0,0]" \
        : "+v"(acc) : "v"(wp), "v"(xv))
#define FMA_MIX_HI(acc, wp, xv) \
    asm("v_fma_mix_f32 %0, %1, %2, %0 op_sel:[1,0,0] op_sel_hi:[1,0,0]" \
        : "+v"(acc) : "v"(wp), "v"(xv))

// ---------------- Kernel A: mu only (R2 compute, single write stream) -------
__global__ __launch_bounds__(256, 4)
void mu_kernel(const float* __restrict__ in,
               const float* __restrict__ w_mu,
               float* __restrict__ out)
{
    __shared__ float lds[3 * ROW_F + 32];

    const int h   = blockIdx.x;
    const int n   = blockIdx.y;
    const int tid = threadIdx.x;
    const int px  = tid >> 5;
    const int c4  = (tid & 31) * 4;

    const float* src = in + (size_t)(n * H_IN + h) * ROW_F;
    if (tid < 144) {
        const f32x4* s4 = reinterpret_cast<const f32x4*>(src) + tid * 4;
        f32x4* d4 = reinterpret_cast<f32x4*>(lds) + tid * 4;
        d4[0] = s4[0]; d4[1] = s4[1]; d4[2] = s4[2]; d4[3] = s4[3];
    }

    unsigned int wpk[27][2];
    #pragma unroll
    for (int kk = 0; kk < 27; ++kk) {
        f32x4 w = *reinterpret_cast<const f32x4*>(w_mu + kk * COUT + c4);
        wpk[kk][0] = (unsigned int)__half_as_ushort(__float2half(w.x))
                   | ((unsigned int)__half_as_ushort(__float2half(w.y)) << 16);
        wpk[kk][1] = (unsigned int)__half_as_ushort(__float2half(w.z))
                   | ((unsigned int)__half_as_ushort(__float2half(w.w)) << 16);
    }

    __syncthreads();

    const size_t pix_base = (size_t)(n * H_OUT + h) * W_OUT;

    #pragma unroll 1
    for (int it = 0; it < 8; ++it) {
        const int p0 = it * 32 + px * 4;

        float mu[4][4];
        #pragma unroll
        for (int j = 0; j < 4; ++j)
            mu[j][0] = mu[j][1] = mu[j][2] = mu[j][3] = 0.f;

        #pragma unroll
        for (int kh = 0; kh < KS; ++kh) {
            const f32x4* rq = reinterpret_cast<const f32x4*>(
                                  &lds[kh * ROW_F + p0 * 3]);
            float r[20];
            *reinterpret_cast<f32x4*>(&r[0])  = rq[0];
            *reinterpret_cast<f32x4*>(&r[4])  = rq[1];
            *reinterpret_cast<f32x4*>(&r[8])  = rq[2];
            *reinterpret_cast<f32x4*>(&r[12]) = rq[3];
            *reinterpret_cast<f32x4*>(&r[16]) = rq[4];

            #pragma unroll
            for (int j = 0; j < 4; ++j) {
                #pragma unroll
                for (int q = 0; q < 9; ++q) {
                    const float x = r[j * 3 + q];
                    const int kk = kh * 9 + q;
                    FMA_MIX_LO(mu[j][0], wpk[kk][0], x);
                    FMA_MIX_HI(mu[j][1], wpk[kk][0], x);
                    FMA_MIX_LO(mu[j][2], wpk[kk][1], x);
                    FMA_MIX_HI(mu[j][3], wpk[kk][1], x);
                }
            }
        }

        #pragma unroll
        for (int j = 0; j < 4; ++j) {
            const int p = p0 + j;
            if (p < W_OUT) {
                const size_t o = (pix_base + p) * COUT + c4;
                f32x4 m = {mu[j][0], mu[j][1], mu[j][2], mu[j][3]};
                *reinterpret_cast<f32x4*>(out + o) = m;
            }
        }
    }
}

// ---------------- Kernel B: sigma only (cheap sumsq, single write stream) ---
__global__ __launch_bounds__(256, 8)
void sigma_kernel(const float* __restrict__ in,
                  const float* __restrict__ w_sigma,
                  float* __restrict__ out_sig)
{
    __shared__ float lds[3 * ROW_F + 32];
    __shared__ float ssrow[W_OUT + 2];

    const int h   = blockIdx.x;
    const int n   = blockIdx.y;
    const int tid = threadIdx.x;
    const int px  = tid >> 5;
    const int c4  = (tid & 31) * 4;

    const float* src = in + (size_t)(n * H_IN + h) * ROW_F;
    if (tid < 144) {
        const f32x4* s4 = reinterpret_cast<const f32x4*>(src) + tid * 4;
        f32x4* d4 = reinterpret_cast<f32x4*>(lds) + tid * 4;
        d4[0] = s4[0]; d4[1] = s4[1]; d4[2] = s4[2]; d4[3] = s4[3];
    }

    f32x4 ws = *reinterpret_cast<const f32x4*>(w_sigma + c4);
    float sp[4];
    sp[0] = log1pf(expf(ws.x));
    sp[1] = log1pf(expf(ws.y));
    sp[2] = log1pf(expf(ws.z));
    sp[3] = log1pf(expf(ws.w));

    __syncthreads();

    // per-pixel sum of squares over the 3x3x3 window
    if (tid < W_OUT) {
        const int base = tid * 3;
        float s = 0.f;
        #pragma unroll
        for (int kh = 0; kh < KS; ++kh) {
            #pragma unroll
            for (int q = 0; q < 9; ++q) {
                const float x = lds[kh * ROW_F + base + q];
                s = fmaf(x, x, s);
            }
        }
        ssrow[tid] = s;
    }
    __syncthreads();

    const size_t pix_base = (size_t)(n * H_OUT + h) * W_OUT;

    #pragma unroll 1
    for (int it = 0; it < 8; ++it) {
        const int p0 = it * 32 + px * 4;
        #pragma unroll
        for (int j = 0; j < 4; ++j) {
            const int p = p0 + j;
            if (p < W_OUT) {
                const float ss = ssrow[p];
                const size_t o = (pix_base + p) * COUT + c4;
                f32x4 sg = {ss * sp[0], ss * sp[1], ss * sp[2], ss * sp[3]};
                *reinterpret_cast<f32x4*>(out_sig + o) = sg;
            }
        }
    }
}

extern "C" void kernel_launch(void* const* d_in, const int* in_sizes, int n_in,
                              void* d_out, int out_size, void* d_ws, size_t ws_size,
                              hipStream_t stream)
{
    const float* in      = (const float*)d_in[0];
    const float* w_mu    = (const float*)d_in[1];
    const float* w_sigma = (const float*)d_in[2];
    float* out           = (float*)d_out;
    float* out_sig       = out + (size_t)NB * H_OUT * W_OUT * COUT;

    dim3 grid(H_OUT, NB);
    dim3 block(256);
    mu_kernel<<<grid, block, 0, stream>>>(in, w_mu, out);
    sigma_kernel<<<grid, block, 0, stream>>>(in, w_sigma, out_sig);
}